// Round 9
// baseline (322.680 us; speedup 1.0000x reference)
//
#include <hip/hip_runtime.h>
#include <math.h>

#define NN 10000
#define NE 100000
#define E2 (NE + NN)
#define NBATCH 64

typedef short bf16x8 __attribute__((ext_vector_type(8)));
typedef float f32x4 __attribute__((ext_vector_type(4)));

// lrelu(v) == max(v, 0.2v) for all v (bit-identical to the branch form; 2 VALU ops)
__device__ __forceinline__ float lrelu(float v){ return fmaxf(v, 0.2f*v); }

// fp32 -> bf16 round-to-nearest-even
__device__ __forceinline__ unsigned short f2bf(float x){
  unsigned int u = __float_as_uint(x);
  u += 0x7fffu + ((u >> 16) & 1u);
  return (unsigned short)(u >> 16);
}
__device__ __forceinline__ float bf2f(unsigned short u){
  return __uint_as_float(((unsigned int)u) << 16);
}

// ---------------- prep: zero + c1 precompute (+CTr) + 4 weight transposes --------------
__global__ __launch_bounds__(256) void prep_kernel(
    const float* __restrict__ vp_w, const float* __restrict__ vp_b,
    const float* __restrict__ type_emb,
    const float* __restrict__ c1_wl, const float* __restrict__ c1_bl,
    const float* __restrict__ c1_wr, const float* __restrict__ c1_br,
    float* __restrict__ Ul, float* __restrict__ CTl,
    float* __restrict__ Ur, float* __restrict__ CTr,
    const float* __restrict__ c2_wl, const float* __restrict__ c2_wr,
    const float* __restrict__ c3_wl, const float* __restrict__ c3_wr,
    unsigned short* __restrict__ W2lT, unsigned short* __restrict__ W2rT,
    unsigned short* __restrict__ W3lT, unsigned short* __restrict__ W3rT,
    float* __restrict__ zbase, int zero_words)
{
  __shared__ float t[64][65];
  int b = blockIdx.x;
  int tid = threadIdx.x;
  if (b < 144){
    const float* in; unsigned short* out; int K, N, idx;
    if (b < 64)      { in=c2_wl; out=W2lT; K=1024; N=256; idx=b; }
    else if (b <128) { in=c2_wr; out=W2rT; K=1024; N=256; idx=b-64; }
    else if (b <136) { in=c3_wl; out=W3lT; K=256;  N=128; idx=b-128; }
    else             { in=c3_wr; out=W3rT; K=256;  N=128; idx=b-136; }
    int K64 = K >> 6;
    int kx = idx % K64, nx = idx / K64;
    int k0 = kx*64, n0 = nx*64;
    int lr = tid >> 4;
    int lc = (tid & 15) * 4;
#pragma unroll
    for (int i=0;i<4;++i){
      int r = lr + i*16;
      float4 v = *(const float4*)(in + (size_t)(k0+r)*N + n0 + lc);
      t[r][lc+0]=v.x; t[r][lc+1]=v.y; t[r][lc+2]=v.z; t[r][lc+3]=v.w;
    }
    __syncthreads();
    int sr = tid >> 3;
    int sc = (tid & 7) * 8;
#pragma unroll
    for (int i=0;i<2;++i){
      int n = sr + i*32;
      unsigned short tmp[8];
#pragma unroll
      for (int j=0;j<8;++j) tmp[j] = f2bf(t[sc+j][n]);
      unsigned short* op = out + (size_t)(n0+n)*K + k0 + sc;
      *(ushort4*)op       = make_ushort4(tmp[0],tmp[1],tmp[2],tmp[3]);
      *(ushort4*)(op + 4) = make_ushort4(tmp[4],tmp[5],tmp[6],tmp[7]);
    }
  } else if (b < 148){
    int j = (b-144)*256 + tid;
    float ul=0.f, c0l=0.f, c1l=0.f, ur=0.f, c0r=0.f, c1r=0.f;
    for (int k=0; k<128; ++k){
      float a = c1_wl[k*1024 + j], bb = c1_wr[k*1024 + j];
      float vw = vp_w[k], vb = vp_b[k], t0 = type_emb[k], t1 = type_emb[128+k];
      ul += vw*a; ur += vw*bb;
      c0l += (vb+t0)*a; c1l += (vb+t1)*a;
      c0r += (vb+t0)*bb; c1r += (vb+t1)*bb;
    }
    float bl = c1_bl[j], br = c1_br[j];
    Ul[j]=ul; Ur[j]=ur;
    CTl[j]      = c0l + bl;
    CTl[1024+j] = c1l + bl;
    CTr[j]      = c0r + br;
    CTr[1024+j] = c1r + br;
  } else {
    for (int i = (b-148)*256 + tid; i < zero_words; i += 32*256)
      zbase[i] = 0.f;
  }
}

// ---------------- CSR build: 3 kernels (count -> scan -> fill) ----------------
__global__ void count_kernel(const int* __restrict__ dst, const float* __restrict__ ea,
                             int* __restrict__ deg, float* __restrict__ loop_sum){
  int e = blockIdx.x*256 + threadIdx.x;
  if (e < NE){
    int d = dst[e];
    atomicAdd(&deg[d], 1);
    atomicAdd(&loop_sum[d], ea[e]);
  }
}

// Single-block 3-phase scan (10 elems/thread). Emits the SELF-LOOP-AUGMENTED CSR:
// rowptr2[n] = excl_scan(deg)[n] + n  (each row gets one extra slot at the FRONT
// holding the self-loop edge {n, loop_attr_bits}), plus the packed node table
// xt[n] = {x[n], (float)ntype[n]}. Also initializes the 8-entry se pad past E2
// (downstream kernels over-read unconditionally; pad must hold VALID node ids).
__global__ __launch_bounds__(1024) void scan_kernel(const int* __restrict__ deg,
    const float* __restrict__ loop_sum, const float* __restrict__ x,
    const int* __restrict__ ntype,
    int* __restrict__ rowptr, int2* __restrict__ se, float2* __restrict__ xt){
  __shared__ int wtot[16];
  int tid = threadIdx.x;
  int lane = tid & 63, wid = tid >> 6;
  int base = tid*10;
  int d[10]; int run = 0;
#pragma unroll
  for (int j=0;j<10;++j){
    int i = base + j;
    int v = (i < NN) ? deg[i] : 0;
    run += v; d[j] = run;                 // local inclusive
  }
  int T = run;
  int incl = T;
#pragma unroll
  for (int off=1; off<64; off<<=1){
    int s = __shfl_up(incl, off, 64);
    if (lane >= off) incl += s;
  }
  if (lane == 63) wtot[wid] = incl;
  __syncthreads();
  int wpre = 0;
  for (int w2=0; w2<wid; ++w2) wpre += wtot[w2];
  int ebase = wpre + incl - T;            // exclusive prefix of this thread's range
#pragma unroll
  for (int j=0;j<10;++j){
    int i = base + j;
    if (i < NN){
      int v = d[j] - ((j==0) ? 0 : d[j-1]);
      int rp2 = ebase + d[j] - v + i;     // rowptr2[i]
      rowptr[i] = rp2;
      float la = loop_sum[i] / fmaxf((float)v, 1.f);   // fill='mean'
      se[rp2] = make_int2(i, __float_as_int(la));      // self-loop at row front
      xt[i] = make_float2(x[i], (float)ntype[i]);
    }
  }
  if (tid == 1023){
    int tot = wpre + incl + NN;           // == E2
    rowptr[NN] = tot;
#pragma unroll
    for (int k=0; k<8; ++k) se[tot+k] = make_int2(0, 0);  // safe pad (node 0, ea=0)
  }
}

__global__ void fill_kernel(const int* __restrict__ src, const int* __restrict__ dst,
                            const float* __restrict__ ea, const int* __restrict__ rowptr,
                            int* __restrict__ rowctr, int2* __restrict__ se){
  int e = blockIdx.x*256 + threadIdx.x;
  if (e < NE){
    int d = dst[e];
    int p = rowptr[d] + 1 + atomicAdd(&rowctr[d], 1);   // +1: slot 0 = self-loop
    se[p] = make_int2(src[e], __float_as_int(ea[e]));
  }
}

// ---------------- conv1 FUSED: persistent blocks + LDS-resident node table ------------
// 512 blocks (2/CU at 80 KB LDS). Each block stages the full xt[10000] table into
// LDS once, then grid-strides over node PAIRS (128 thr/node, 8 ch/lane, 16 lanes/
// head). The per-edge gather chain se[j] -> xt[src] becomes se (stream, L1) ->
// sxt (LDS BROADCAST: all 128 threads of a node read the same entry -> 0 conflicts,
// ~64cy) — hidden by the 2-edge interleaved pipeline. All channel constants hoisted
// to registers across the node loop. Math identical to r8 (2-edge pipeline,
// att*lrelu = 0.6att*z + 0.4att*|z| fold, plain-exp softmax).
__global__ __launch_bounds__(256) void conv1_fused(
    const int* __restrict__ rowptr, const int2* __restrict__ se,
    const float2* __restrict__ xt,
    const float* __restrict__ Ul, const float* __restrict__ Ur,
    const float* __restrict__ CTl, const float* __restrict__ CTr,
    const float* __restrict__ we, const float* __restrict__ att,
    const float* __restrict__ bias, unsigned short* __restrict__ out)
{
  __shared__ float2 sxt[NN];               // 80 KB
  int tid = threadIdx.x;
  for (int i = tid; i < NN/2; i += 256)
    ((float4*)sxt)[i] = ((const float4*)xt)[i];
  __syncthreads();
  int te = tid & 127;
  int half = tid >> 7;
  int ch0 = te * 8;                        // head = te>>4
  // channel constants, register-resident across all nodes
  float ul[8], wev[8], a1[8], a2[8], ctl0[8], ctl1[8], ctr0[8], ctrd[8], urv[8];
#pragma unroll
  for (int v=0; v<8; ++v){
    ul[v]=Ul[ch0+v]; wev[v]=we[ch0+v];
    float av = att[ch0+v]; a1[v]=0.6f*av; a2[v]=0.4f*av;
    ctl0[v]=CTl[ch0+v]; ctl1[v]=CTl[1024+ch0+v];
    float r0 = CTr[ch0+v], r1 = CTr[1024+ch0+v];
    ctr0[v]=r0; ctrd[v]=r1-r0;
    urv[v]=Ur[ch0+v];
  }
  const int stride = gridDim.x*2;
  for (int n0 = blockIdx.x*2; n0 < NN; n0 += stride){
    int n = n0 + half;                     // NN even, n0 even -> n < NN always
    int beg = rowptr[n], cnt = rowptr[n+1]-beg;   // cnt = deg+1, self at slot 0
    float2 xtn = sxt[n];
    float cn0[8], cnd[8];
#pragma unroll
    for (int v=0; v<8; ++v){
      float ctr = fmaf(xtn.y, ctrd[v], ctr0[v]);           // type-select via fma
      cn0[v] = fmaf(xtn.x, urv[v], ctr) + ctl0[v];
      cnd[v] = ctl1[v] - ctl0[v];
    }
    const int2* sp = se + beg;
    // pipeline prologue: unconditional over-reads land in neighbor rows / pad (valid)
    int2 q0 = sp[0], q1 = sp[1], q2 = sp[2], q3 = sp[3];
    float2 x0 = sxt[q0.x], x1 = sxt[q1.x];
    float la_=0.f, lb_=0.f, s1a=0.f, s1b=0.f, sta=0.f, stb=0.f;
    int npair = cnt >> 1;
    for (int p=0; p<npair; ++p){
      int i = p*2;
      float2 x2 = sxt[q2.x], x3 = sxt[q3.x];
      int2 q4 = sp[i+4], q5 = sp[i+5];
      float xs0=x0.x, tf0=x0.y, ea0=__int_as_float(q0.y);
      float xs1=x1.x, tf1=x1.y, ea1=__int_as_float(q1.y);
      float p0a=0.f,p0b=0.f,p1a=0.f,p1b=0.f;
#pragma unroll
      for (int v=0; v<8; ++v){
        float z0 = fmaf(xs0, ul[v], fmaf(ea0, wev[v], fmaf(tf0, cnd[v], cn0[v])));
        float z1 = fmaf(xs1, ul[v], fmaf(ea1, wev[v], fmaf(tf1, cnd[v], cn0[v])));
        p0a = fmaf(a1[v], z0, p0a); p0b = fmaf(a2[v], fabsf(z0), p0b);
        p1a = fmaf(a1[v], z1, p1a); p1b = fmaf(a2[v], fabsf(z1), p1b);
      }
      float p0 = p0a+p0b, p1 = p1a+p1b;
#pragma unroll
      for (int mm=1; mm<16; mm<<=1){
        p0 += __shfl_xor(p0, mm, 16);
        p1 += __shfl_xor(p1, mm, 16);
      }
      float pe0 = __expf(p0), pe1 = __expf(p1);
      la_ += pe0; lb_ += pe1;
      s1a = fmaf(pe0, xs0, s1a); s1b = fmaf(pe1, xs1, s1b);
      sta = fmaf(pe0, tf0, sta); stb = fmaf(pe1, tf1, stb);
      q0=q2; x0=x2; q1=q3; x1=x3; q2=q4; q3=q5;
    }
    if (cnt & 1){
      float xs0=x0.x, tf0=x0.y, ea0=__int_as_float(q0.y);
      float p0a=0.f,p0b=0.f;
#pragma unroll
      for (int v=0; v<8; ++v){
        float z0 = fmaf(xs0, ul[v], fmaf(ea0, wev[v], fmaf(tf0, cnd[v], cn0[v])));
        p0a = fmaf(a1[v], z0, p0a); p0b = fmaf(a2[v], fabsf(z0), p0b);
      }
      float p0 = p0a+p0b;
#pragma unroll
      for (int mm=1; mm<16; mm<<=1) p0 += __shfl_xor(p0, mm, 16);
      float pe0 = __expf(p0);
      la_ += pe0; s1a = fmaf(pe0, xs0, s1a); sta = fmaf(pe0, tf0, sta);
    }
    float inv = 1.f/(la_+lb_);
    float s1 = (s1a+s1b)*inv;
    float s21 = (sta+stb)*inv;     // weight of type-1 sources
    float s20 = 1.f - s21;         // weight of type-0 sources
    bf16x8 ov;
#pragma unroll
    for (int v=0; v<8; ++v){
      float o = lrelu(fmaf(s1, ul[v], fmaf(s20, ctl0[v], fmaf(s21, ctl1[v], bias[ch0+v]))));
      ov[v] = (short)f2bf(o);
    }
    *(bf16x8*)(out + (size_t)n*1024 + ch0) = ov;
  }
}

// ---------------- generic fused GATv2 conv, QUAD-stream, plain-exp softmax ------------
// Self-augmented CSR: all cnt edges (self first) are real se entries -> branch-free
// quad loop, remainder masked via val[k] (junk gathers read valid node ids from
// neighbor rows / pad). att*lrelu fold: 4 VALU/ch with dual accumulator chains.
template<int H, int NPB, int VPT, bool ONLY0, bool OUTBF, bool INBF>
__global__ __launch_bounds__(64*NPB) void conv_kernel(
    const int* __restrict__ rowptr, const int2* __restrict__ se,
    const int* __restrict__ ntype,
    const void* __restrict__ Xv, int stride, int xr_off,
    const float* __restrict__ we, const float* __restrict__ att, const float* __restrict__ bias,
    void* __restrict__ out)
{
  const int HC = 64*VPT;
  const int TPH = 64/H;
  int n = blockIdx.x*NPB + (threadIdx.x >> 6);
  if (n >= NN) return;
  if (ONLY0 && ntype[n] != 0) return;
  int tid = threadIdx.x & 63;
  int ch0 = tid * VPT;
  const float* Xf = (const float*)Xv;
  const unsigned short* Xb = (const unsigned short*)Xv;
  float wev[VPT], a1v[VPT], a2v[VPT], biv[VPT], xrv[VPT];
#pragma unroll
  for (int v=0; v<VPT; ++v){
    int ch = ch0+v;
    wev[v]=we[ch]; biv[v]=bias[ch];
    float av = att[ch]; a1v[v]=0.6f*av; a2v[v]=0.4f*av;
  }
  if constexpr (INBF){
    ushort4 q = *(const ushort4*)(Xb + (size_t)n*stride + xr_off + ch0);
    xrv[0]=bf2f(q.x); xrv[1]=bf2f(q.y); xrv[2]=bf2f(q.z); xrv[3]=bf2f(q.w);
  } else {
#pragma unroll
    for (int v=0; v<VPT; ++v) xrv[v]=Xf[(size_t)n*stride + xr_off + ch0+v];
  }
  float ls[4], A[4][VPT];
#pragma unroll
  for (int k=0; k<4; ++k){
    ls[k] = 0.f;
#pragma unroll
    for (int v=0; v<VPT; ++v) A[k][v] = 0.f;
  }
  int beg=rowptr[n], end=rowptr[n+1];   // [beg,end): self + real edges
  for (int j=beg; j<end; j+=4){
    bool val[4]; int sx[4]; float ex[4];
#pragma unroll
    for (int k=0; k<4; ++k){
      int pos = j + k;
      val[k] = pos < end;
      int2 q = se[pos];                  // unconditional (padded; junk masked below)
      sx[k] = q.x; ex[k] = __int_as_float(q.y);
    }
    float xv[4][VPT];
#pragma unroll
    for (int k=0; k<4; ++k){
      if constexpr (INBF){
        ushort4 q = *(const ushort4*)(Xb + (size_t)sx[k]*stride + ch0);
        xv[k][0]=bf2f(q.x); xv[k][1]=bf2f(q.y); xv[k][2]=bf2f(q.z); xv[k][3]=bf2f(q.w);
      } else if constexpr (VPT == 4){
        float4 q = *(const float4*)(Xf + (size_t)sx[k]*stride + ch0);
        xv[k][0]=q.x; xv[k][1]=q.y; xv[k][2]=q.z; xv[k][3]=q.w;
      } else {
        float2 q = *(const float2*)(Xf + (size_t)sx[k]*stride + ch0);
        xv[k][0]=q.x; xv[k][1]=q.y;
      }
    }
    float p[4];
#pragma unroll
    for (int k=0; k<4; ++k){
      float pa = 0.f, pb = 0.f;
#pragma unroll
      for (int v=0; v<VPT; ++v){
        float z = fmaf(ex[k], wev[v], xv[k][v]+xrv[v]);
        pa = fmaf(a1v[v], z, pa);
        pb = fmaf(a2v[v], fabsf(z), pb);
      }
      p[k] = pa + pb;
    }
#pragma unroll
    for (int mm=1; mm<TPH; mm<<=1){
#pragma unroll
      for (int k=0; k<4; ++k) p[k] += __shfl_xor(p[k], mm, 64);
    }
#pragma unroll
    for (int k=0; k<4; ++k){
      float pe = val[k] ? __expf(p[k]) : 0.f;
      ls[k] += pe;
#pragma unroll
      for (int v=0; v<VPT; ++v) A[k][v] = fmaf(pe, xv[k][v], A[k][v]);
    }
  }
  float lt = (ls[0]+ls[1]) + (ls[2]+ls[3]);
  float inv = 1.f/lt;
  size_t baseo=(size_t)n*HC+ch0;
  if constexpr (OUTBF){
    unsigned short* ob = (unsigned short*)out;
    ushort4 o;
    o.x = f2bf(lrelu(((A[0][0]+A[1][0])+(A[2][0]+A[3][0]))*inv+biv[0]));
    o.y = f2bf(lrelu(((A[0][1]+A[1][1])+(A[2][1]+A[3][1]))*inv+biv[1]));
    o.z = f2bf(lrelu(((A[0][2]+A[1][2])+(A[2][2]+A[3][2]))*inv+biv[2]));
    o.w = f2bf(lrelu(((A[0][3]+A[1][3])+(A[2][3]+A[3][3]))*inv+biv[3]));
    *(ushort4*)(ob + baseo) = o;
  } else {
    float* of = (float*)out;
#pragma unroll
    for (int v=0; v<VPT; ++v)
      of[baseo+v] = lrelu(((A[0][v]+A[1][v])+(A[2][v]+A[3][v]))*inv+biv[v]);
  }
}

// ---------------- bf16 MFMA dual GEMM, LDS-staged via global_load_lds (m97 style) -----
template<bool OUTBF>
__global__ __launch_bounds__(256) void gemm_dual_lds(
    const short* __restrict__ Abf,
    const short* __restrict__ WlT, const short* __restrict__ WrT,
    const float* __restrict__ bl, const float* __restrict__ br,
    void* __restrict__ Out, int M, int K, int NcH, int cgrid, int rgrid)
{
  __shared__ short lds[12288];    // A: [0,8192) shorts (128 rows x 64), B: [8192,12288)
  int id = blockIdx.x;
  int xcd = id & 7, slot = id >> 3;
  int nb = slot % cgrid;
  int rowgroup = (slot / cgrid) * 8 + xcd;
  if (rowgroup >= rgrid) return;
  int row0 = rowgroup * 128;
  int NC2 = 2*NcH;
  int halfx = NcH >> 6;
  int isR = nb >= halfx;
  const short* WT = isR ? WrT : WlT;
  const float* bias = isR ? br : bl;
  int col0 = (nb - (isR ? halfx : 0)) * 64;
  int gcol0 = nb * 64;
  int tid = threadIdx.x;
  int lane = tid & 63, wave = tid >> 6;
  int wm = wave >> 1, wn = wave & 1;
  int quad = lane >> 4, l16 = lane & 15;

  const short* asrc[4];
#pragma unroll
  for (int i=0;i<4;++i){
    int c = wave*256 + i*64 + lane;
    int m = c >> 3, j = c & 7;
    int gr = row0 + m; gr = gr < M ? gr : M-1;   // clamp; never stored
    asrc[i] = Abf + (size_t)gr*K + ((j ^ (m & 7)) << 3);
  }
  const short* bsrc[2];
#pragma unroll
  for (int i=0;i<2;++i){
    int c = wave*128 + i*64 + lane;
    int nloc = c >> 3, j = c & 7;
    bsrc[i] = WT + (size_t)(col0 + nloc)*K + ((j ^ (nloc & 7)) << 3);
  }

  float biasv[2] = { bias[col0 + wn*32 + l16], bias[col0 + wn*32 + 16 + l16] };
  f32x4 acc[4][2];
#pragma unroll
  for (int f=0; f<4; ++f)
#pragma unroll
    for (int g=0; g<2; ++g) acc[f][g] = (f32x4){0.f,0.f,0.f,0.f};

  int niter = K >> 6;
  for (int it=0; it<niter; ++it){
    int k0 = it << 6;
#pragma unroll
    for (int i=0;i<4;++i)
      __builtin_amdgcn_global_load_lds(asrc[i] + k0, &lds[(wave*256 + i*64)*8], 16, 0, 0);
#pragma unroll
    for (int i=0;i<2;++i)
      __builtin_amdgcn_global_load_lds(bsrc[i] + k0, &lds[8192 + (wave*128 + i*64)*8], 16, 0, 0);
    __syncthreads();
#pragma unroll
    for (int s=0; s<2; ++s){
      int t = s*4 + quad;
      bf16x8 af[4], bfv[2];
#pragma unroll
      for (int f=0; f<4; ++f){
        int m = wm*64 + f*16 + l16;
        af[f] = *(const bf16x8*)&lds[m*64 + ((t ^ (m & 7)) << 3)];
      }
#pragma unroll
      for (int g=0; g<2; ++g){
        int nloc = wn*32 + g*16 + l16;
        bfv[g] = *(const bf16x8*)&lds[8192 + nloc*64 + ((t ^ (nloc & 7)) << 3)];
      }
#pragma unroll
      for (int f=0; f<4; ++f)
#pragma unroll
        for (int g=0; g<2; ++g)
          acc[f][g] = __builtin_amdgcn_mfma_f32_16x16x32_bf16(af[f], bfv[g], acc[f][g], 0,0,0);
    }
    __syncthreads();
  }

#pragma unroll
  for (int f=0; f<4; ++f){
    int rbase = row0 + wm*64 + f*16 + quad*4;
#pragma unroll
    for (int r=0; r<4; ++r){
      int rr = rbase + r;
      if (rr < M){
#pragma unroll
        for (int g=0; g<2; ++g){
          int cc = gcol0 + wn*32 + g*16 + l16;
          float val = acc[f][g][r] + biasv[g];
          if constexpr (OUTBF) ((unsigned short*)Out)[(size_t)rr*NC2 + cc] = f2bf(val);
          else                 ((float*)Out)[(size_t)rr*NC2 + cc] = val;
        }
      }
    }
  }
}

// ---------------- fused pool (sorted batch, binary search) + MLP head ----------------
__device__ __forceinline__ int lbound(const int* __restrict__ a, int n, int key){
  int lo = 0, hi = n;
  while (lo < hi){ int mid = (lo+hi) >> 1; if (a[mid] < key) lo = mid+1; else hi = mid; }
  return lo;
}

__global__ __launch_bounds__(128) void head_kernel(
    const float* __restrict__ h3, const int* __restrict__ ntype, const int* __restrict__ batch,
    const float* __restrict__ m1w, const float* __restrict__ m1b,
    const float* __restrict__ g1, const float* __restrict__ b1,
    const float* __restrict__ m2w, const float* __restrict__ m2b,
    const float* __restrict__ g2, const float* __restrict__ b2,
    const float* __restrict__ m3w, const float* __restrict__ m3b,
    float* __restrict__ out)
{
  __shared__ float p[128];
  __shared__ float hb[128];
  __shared__ float red[128];
  int b = blockIdx.x, j = threadIdx.x;
  int lo = lbound(batch, NN, b);
  int hi = lbound(batch, NN, b+1);
  float s = 0.f, cnt = 0.f;
  int n = lo;
  for (; n + 3 < hi; n += 4){
    float w0 = (ntype[n]   == 0) ? 1.f : 0.f;
    float w1 = (ntype[n+1] == 0) ? 1.f : 0.f;
    float w2 = (ntype[n+2] == 0) ? 1.f : 0.f;
    float w3 = (ntype[n+3] == 0) ? 1.f : 0.f;
    s += w0*h3[(size_t)n*128 + j]     + w1*h3[(size_t)(n+1)*128 + j]
       + w2*h3[(size_t)(n+2)*128 + j] + w3*h3[(size_t)(n+3)*128 + j];
    cnt += w0 + w1 + w2 + w3;
  }
  for (; n < hi; ++n){
    float w = (ntype[n] == 0) ? 1.f : 0.f;
    s += w*h3[(size_t)n*128 + j];
    cnt += w;
  }
  p[j] = s / fmaxf(cnt, 1.f);
  __syncthreads();
  float a = m1b[j];
  for (int k=0; k<128; ++k) a += p[k]*m1w[k*128 + j];
  red[j] = a; __syncthreads();
  for (int off=64; off>0; off>>=1){ if (j<off) red[j] += red[j+off]; __syncthreads(); }
  float mu = red[0] * (1.f/128.f);
  __syncthreads();
  float d = a - mu;
  red[j] = d*d; __syncthreads();
  for (int off=64; off>0; off>>=1){ if (j<off) red[j] += red[j+off]; __syncthreads(); }
  float var = red[0] * (1.f/128.f);
  __syncthreads();
  hb[j] = lrelu(d * rsqrtf(var + 1e-5f) * g1[j] + b1[j]);
  __syncthreads();
  float a2 = 0.f;
  if (j < 64){
    a2 = m2b[j];
    for (int k=0; k<128; ++k) a2 += hb[k]*m2w[k*64 + j];
  }
  red[j] = (j<64) ? a2 : 0.f; __syncthreads();
  for (int off=64; off>0; off>>=1){ if (j<off) red[j] += red[j+off]; __syncthreads(); }
  float mu2 = red[0] * (1.f/64.f);
  __syncthreads();
  float d2 = a2 - mu2;
  red[j] = (j<64) ? d2*d2 : 0.f; __syncthreads();
  for (int off=64; off>0; off>>=1){ if (j<off) red[j] += red[j+off]; __syncthreads(); }
  float var2 = red[0] * (1.f/64.f);
  __syncthreads();
  if (j < 64) hb[j] = lrelu(d2 * rsqrtf(var2 + 1e-5f) * g2[j] + b2[j]);
  __syncthreads();
  if (j == 0){
    float o = m3b[0];
    for (int k=0; k<64; ++k) o += hb[k]*m3w[k];
    out[b] = o;
  }
}

extern "C" void kernel_launch(void* const* d_in, const int* in_sizes, int n_in,
                              void* d_out, int out_size, void* d_ws, size_t ws_size,
                              hipStream_t stream)
{
  const float* x        = (const float*)d_in[0];
  const int*   ntype    = (const int*)d_in[1];
  const int*   ei       = (const int*)d_in[2];
  const float* eattr    = (const float*)d_in[3];
  const int*   batch    = (const int*)d_in[4];
  const float* vp_w     = (const float*)d_in[5];
  const float* vp_b     = (const float*)d_in[6];
  const float* type_emb = (const float*)d_in[7];
  const float* c1_wl = (const float*)d_in[8];  const float* c1_bl = (const float*)d_in[9];
  const float* c1_wr = (const float*)d_in[10]; const float* c1_br = (const float*)d_in[11];
  const float* c1_we = (const float*)d_in[12]; const float* c1_att= (const float*)d_in[13];
  const float* c1_bias=(const float*)d_in[14];
  const float* c2_wl = (const float*)d_in[15]; const float* c2_bl = (const float*)d_in[16];
  const float* c2_wr = (const float*)d_in[17]; const float* c2_br = (const float*)d_in[18];
  const float* c2_we = (const float*)d_in[19]; const float* c2_att= (const float*)d_in[20];
  const float* c2_bias=(const float*)d_in[21];
  const float* c3_wl = (const float*)d_in[22]; const float* c3_bl = (const float*)d_in[23];
  const float* c3_wr = (const float*)d_in[24]; const float* c3_br = (const float*)d_in[25];
  const float* c3_we = (const float*)d_in[26]; const float* c3_att= (const float*)d_in[27];
  const float* c3_bias=(const float*)d_in[28];
  const float* m1_w = (const float*)d_in[29]; const float* m1_b = (const float*)d_in[30];
  const float* ln1_g= (const float*)d_in[31]; const float* ln1_b= (const float*)d_in[32];
  const float* m2_w = (const float*)d_in[33]; const float* m2_b = (const float*)d_in[34];
  const float* ln2_g= (const float*)d_in[35]; const float* ln2_b= (const float*)d_in[36];
  const float* m3_w = (const float*)d_in[37]; const float* m3_b = (const float*)d_in[38];
  const int* esrc = ei;
  const int* edst = ei + NE;
  float* outp = (float*)d_out;
  (void)in_sizes; (void)n_in; (void)out_size; (void)ws_size;

  // ---- workspace arena ----
  char* w = (char*)d_ws;
  auto alloc = [&](size_t bytes) -> void* {
    void* p = (void*)w;
    w += (bytes + 255) & ~(size_t)255;
    return p;
  };
  unsigned short* h1bf = (unsigned short*)alloc((size_t)NN*1024*2);  // conv1 out, bf16
  unsigned short* X2   = (unsigned short*)alloc((size_t)NN*512*2);   // [xl2 | xr2] bf16
  unsigned short* h2bf = (unsigned short*)alloc((size_t)NN*256*2);   // conv2 out, bf16
  float* X3   = (float*)alloc((size_t)NN*256*4);    // [xl3 | xr3] fp32
  float* h3   = (float*)alloc((size_t)NN*128*4);    // conv3 out (type0 rows only)
  unsigned short* W2lT = (unsigned short*)alloc((size_t)256*1024*2);
  unsigned short* W2rT = (unsigned short*)alloc((size_t)256*1024*2);
  unsigned short* W3lT = (unsigned short*)alloc((size_t)128*256*2);
  unsigned short* W3rT = (unsigned short*)alloc((size_t)128*256*2);
  float* Ul   = (float*)alloc(1024*4);
  float* CTl  = (float*)alloc(2048*4);
  float* Ur   = (float*)alloc(1024*4);
  float* CTr  = (float*)alloc(2048*4);
  const int zero_words = 3*NN;                       // deg, rowctr, loop_sum
  float* zbase = (float*)alloc((size_t)zero_words*4);
  int*   deg      = (int*)zbase;
  int*   rowctr   = (int*)(zbase + NN);
  float* loop_sum = zbase + 2*NN;
  float2* xt      = (float2*)alloc((size_t)NN*8);    // {x, (float)ntype}
  int*   rowptr   = (int*)alloc((size_t)(NN+1)*4);   // self-augmented rowptr2
  int2*  se       = (int2*)alloc((size_t)(E2+8)*8);  // self+edges CSR, +8 pad

  // ---- pipeline (10 dispatches) ----
  prep_kernel<<<180, 256, 0, stream>>>(vp_w, vp_b, type_emb,
      c1_wl, c1_bl, c1_wr, c1_br, Ul, CTl, Ur, CTr,
      c2_wl, c2_wr, c3_wl, c3_wr, W2lT, W2rT, W3lT, W3rT,
      zbase, zero_words);
  count_kernel<<<(NE+255)/256, 256, 0, stream>>>(edst, eattr, deg, loop_sum);
  scan_kernel<<<1, 1024, 0, stream>>>(deg, loop_sum, x, ntype, rowptr, se, xt);
  fill_kernel<<<(NE+255)/256, 256, 0, stream>>>(esrc, edst, eattr, rowptr, rowctr, se);
  conv1_fused<<<512, 256, 0, stream>>>(rowptr, se, xt,
      Ul, Ur, CTl, CTr, c1_we, c1_att, c1_bias, h1bf);
  // c2: X2[10000,512] bf16, K=1024, NcH=256: cgrid=8, rgrid=79 -> 640 blocks
  gemm_dual_lds<true><<<640, 256, 0, stream>>>(
      (const short*)h1bf, (const short*)W2lT, (const short*)W2rT, c2_bl, c2_br,
      (void*)X2, NN, 1024, 256, 8, 79);
  conv_kernel<2,4,4,false,true,true><<<NN/4, 256, 0, stream>>>(rowptr, se, ntype,
      (const void*)X2, 512, 256, c2_we, c2_att, c2_bias, h2bf);
  // c3: X3[10000,256] fp32, K=256, NcH=128: cgrid=4, rgrid=79 -> 320 blocks
  gemm_dual_lds<false><<<320, 256, 0, stream>>>(
      (const short*)h2bf, (const short*)W3lT, (const short*)W3rT, c3_bl, c3_br,
      (void*)X3, NN, 256, 128, 4, 79);
  conv_kernel<1,4,2,true,false,false><<<NN/4, 256, 0, stream>>>(rowptr, se, ntype,
      (const void*)X3, 256, 128, c3_we, c3_att, c3_bias, h3);
  head_kernel<<<NBATCH, 128, 0, stream>>>(h3, ntype, batch, m1_w, m1_b, ln1_g, ln1_b,
                                          m2_w, m2_b, ln2_g, ln2_b, m3_w, m3_b, outp);
}

// Round 10
// 310.156 us; speedup vs baseline: 1.0404x; 1.0404x over previous
//
#include <hip/hip_runtime.h>
#include <math.h>

#define NN 10000
#define NE 100000
#define E2 (NE + NN)
#define NBATCH 64

typedef short bf16x8 __attribute__((ext_vector_type(8)));
typedef float f32x4 __attribute__((ext_vector_type(4)));

// lrelu(v) == max(v, 0.2v) for all v (bit-identical to the branch form; 2 VALU ops)
__device__ __forceinline__ float lrelu(float v){ return fmaxf(v, 0.2f*v); }

// fp32 -> bf16 round-to-nearest-even
__device__ __forceinline__ unsigned short f2bf(float x){
  unsigned int u = __float_as_uint(x);
  u += 0x7fffu + ((u >> 16) & 1u);
  return (unsigned short)(u >> 16);
}
__device__ __forceinline__ float bf2f(unsigned short u){
  return __uint_as_float(((unsigned int)u) << 16);
}

// ---------------- prep: zero + c1 precompute (+CTr) + 4 weight transposes --------------
__global__ __launch_bounds__(256) void prep_kernel(
    const float* __restrict__ vp_w, const float* __restrict__ vp_b,
    const float* __restrict__ type_emb,
    const float* __restrict__ c1_wl, const float* __restrict__ c1_bl,
    const float* __restrict__ c1_wr, const float* __restrict__ c1_br,
    float* __restrict__ Ul, float* __restrict__ CTl,
    float* __restrict__ Ur, float* __restrict__ CTr,
    const float* __restrict__ c2_wl, const float* __restrict__ c2_wr,
    const float* __restrict__ c3_wl, const float* __restrict__ c3_wr,
    unsigned short* __restrict__ W2lT, unsigned short* __restrict__ W2rT,
    unsigned short* __restrict__ W3lT, unsigned short* __restrict__ W3rT,
    float* __restrict__ zbase, int zero_words)
{
  __shared__ float t[64][65];
  int b = blockIdx.x;
  int tid = threadIdx.x;
  if (b < 144){
    const float* in; unsigned short* out; int K, N, idx;
    if (b < 64)      { in=c2_wl; out=W2lT; K=1024; N=256; idx=b; }
    else if (b <128) { in=c2_wr; out=W2rT; K=1024; N=256; idx=b-64; }
    else if (b <136) { in=c3_wl; out=W3lT; K=256;  N=128; idx=b-128; }
    else             { in=c3_wr; out=W3rT; K=256;  N=128; idx=b-136; }
    int K64 = K >> 6;
    int kx = idx % K64, nx = idx / K64;
    int k0 = kx*64, n0 = nx*64;
    int lr = tid >> 4;
    int lc = (tid & 15) * 4;
#pragma unroll
    for (int i=0;i<4;++i){
      int r = lr + i*16;
      float4 v = *(const float4*)(in + (size_t)(k0+r)*N + n0 + lc);
      t[r][lc+0]=v.x; t[r][lc+1]=v.y; t[r][lc+2]=v.z; t[r][lc+3]=v.w;
    }
    __syncthreads();
    int sr = tid >> 3;
    int sc = (tid & 7) * 8;
#pragma unroll
    for (int i=0;i<2;++i){
      int n = sr + i*32;
      unsigned short tmp[8];
#pragma unroll
      for (int j=0;j<8;++j) tmp[j] = f2bf(t[sc+j][n]);
      unsigned short* op = out + (size_t)(n0+n)*K + k0 + sc;
      *(ushort4*)op       = make_ushort4(tmp[0],tmp[1],tmp[2],tmp[3]);
      *(ushort4*)(op + 4) = make_ushort4(tmp[4],tmp[5],tmp[6],tmp[7]);
    }
  } else if (b < 148){
    int j = (b-144)*256 + tid;
    float ul=0.f, c0l=0.f, c1l=0.f, ur=0.f, c0r=0.f, c1r=0.f;
    for (int k=0; k<128; ++k){
      float a = c1_wl[k*1024 + j], bb = c1_wr[k*1024 + j];
      float vw = vp_w[k], vb = vp_b[k], t0 = type_emb[k], t1 = type_emb[128+k];
      ul += vw*a; ur += vw*bb;
      c0l += (vb+t0)*a; c1l += (vb+t1)*a;
      c0r += (vb+t0)*bb; c1r += (vb+t1)*bb;
    }
    float bl = c1_bl[j], br = c1_br[j];
    Ul[j]=ul; Ur[j]=ur;
    CTl[j]      = c0l + bl;
    CTl[1024+j] = c1l + bl;
    CTr[j]      = c0r + br;
    CTr[1024+j] = c1r + br;
  } else {
    for (int i = (b-148)*256 + tid; i < zero_words; i += 32*256)
      zbase[i] = 0.f;
  }
}

// ---------------- CSR build: 3 kernels (count -> scan -> fill) ----------------
__global__ void count_kernel(const int* __restrict__ dst, const float* __restrict__ ea,
                             int* __restrict__ deg, float* __restrict__ loop_sum){
  int e = blockIdx.x*256 + threadIdx.x;
  if (e < NE){
    int d = dst[e];
    atomicAdd(&deg[d], 1);
    atomicAdd(&loop_sum[d], ea[e]);
  }
}

// Single-block 3-phase scan (10 elems/thread). Emits the SELF-LOOP-AUGMENTED CSR:
// rowptr2[n] = excl_scan(deg)[n] + n  (each row gets one extra slot at the FRONT
// holding the self-loop edge {n, loop_attr_bits}), plus the packed node table
// xt[n] = {x[n], (float)ntype[n]}. Also initializes the 8-entry se pad past E2
// (downstream kernels over-read unconditionally; pad must hold VALID node ids).
__global__ __launch_bounds__(1024) void scan_kernel(const int* __restrict__ deg,
    const float* __restrict__ loop_sum, const float* __restrict__ x,
    const int* __restrict__ ntype,
    int* __restrict__ rowptr, int2* __restrict__ se, float2* __restrict__ xt){
  __shared__ int wtot[16];
  int tid = threadIdx.x;
  int lane = tid & 63, wid = tid >> 6;
  int base = tid*10;
  int d[10]; int run = 0;
#pragma unroll
  for (int j=0;j<10;++j){
    int i = base + j;
    int v = (i < NN) ? deg[i] : 0;
    run += v; d[j] = run;                 // local inclusive
  }
  int T = run;
  int incl = T;
#pragma unroll
  for (int off=1; off<64; off<<=1){
    int s = __shfl_up(incl, off, 64);
    if (lane >= off) incl += s;
  }
  if (lane == 63) wtot[wid] = incl;
  __syncthreads();
  int wpre = 0;
  for (int w2=0; w2<wid; ++w2) wpre += wtot[w2];
  int ebase = wpre + incl - T;            // exclusive prefix of this thread's range
#pragma unroll
  for (int j=0;j<10;++j){
    int i = base + j;
    if (i < NN){
      int v = d[j] - ((j==0) ? 0 : d[j-1]);
      int rp2 = ebase + d[j] - v + i;     // rowptr2[i]
      rowptr[i] = rp2;
      float la = loop_sum[i] / fmaxf((float)v, 1.f);   // fill='mean'
      se[rp2] = make_int2(i, __float_as_int(la));      // self-loop at row front
      xt[i] = make_float2(x[i], (float)ntype[i]);
    }
  }
  if (tid == 1023){
    int tot = wpre + incl + NN;           // == E2
    rowptr[NN] = tot;
#pragma unroll
    for (int k=0; k<8; ++k) se[tot+k] = make_int2(0, 0);  // safe pad (node 0, ea=0)
  }
}

__global__ void fill_kernel(const int* __restrict__ src, const int* __restrict__ dst,
                            const float* __restrict__ ea, const int* __restrict__ rowptr,
                            int* __restrict__ rowctr, int2* __restrict__ se){
  int e = blockIdx.x*256 + threadIdx.x;
  if (e < NE){
    int d = dst[e];
    int p = rowptr[d] + 1 + atomicAdd(&rowctr[d], 1);   // +1: slot 0 = self-loop
    se[p] = make_int2(src[e], __float_as_int(ea[e]));
  }
}

// ---------------- conv1 FUSED: 2 nodes/block, 128 thr/node, 2-edge pipeline ----------
// (r8 version — proven best at 46.0 µs. r9's LDS-resident table regressed: 80 KB
// LDS cut occupancy 28.5->16.5% and the xt gathers were already L1/L2-resident.)
// Lane te owns 8 ch (head = te>>4, 16 lanes/head). Per edge:
// z = xs*ul + ea*we + fmaf(tf,cnd,cn0);  att*lrelu(z) = (0.6att)z + (0.4att)|z|
// (|z| is a free input modifier) -> 5 VALU/ch, dual accumulator chains. TWO edges
// per iteration: independent channel loops / butterflies / exps overlap the
// ds_swizzle and gather latencies. All edge loads unconditional (se padded with
// valid node ids, CSR self-augmented), plain-exp softmax (scores bounded, no max).
__global__ __launch_bounds__(256) void conv1_fused(
    const int* __restrict__ rowptr, const int2* __restrict__ se,
    const float2* __restrict__ xt,
    const float* __restrict__ Ul, const float* __restrict__ Ur,
    const float* __restrict__ CTl, const float* __restrict__ CTr,
    const float* __restrict__ we, const float* __restrict__ att,
    const float* __restrict__ bias, unsigned short* __restrict__ out)
{
  int n = blockIdx.x*2 + (threadIdx.x >> 7);
  if (n >= NN) return;
  int te = threadIdx.x & 127;
  int ch0 = te * 8;                      // head = te>>4
  float ul[8], wev[8], a1[8], a2[8], cn0[8], cnd[8];
#pragma unroll
  for (int v=0; v<8; ++v){
    ul[v]=Ul[ch0+v]; wev[v]=we[ch0+v];
    float av = att[ch0+v]; a1[v]=0.6f*av; a2[v]=0.4f*av;
  }
  int beg = rowptr[n], cnt = rowptr[n+1]-beg;   // cnt = deg+1, self at slot 0
  float2 xtn = xt[n];
  const float* ctr = (xtn.y != 0.f) ? (CTr+1024) : CTr;
#pragma unroll
  for (int v=0; v<8; ++v){
    float c0 = CTl[ch0+v], c1 = CTl[1024+ch0+v];
    cn0[v] = fmaf(xtn.x, Ur[ch0+v], ctr[ch0+v]) + c0;
    cnd[v] = c1 - c0;
  }
  const int2* sp = se + beg;
  // pipeline prologue: unconditional over-reads land in neighbor rows / pad (valid)
  int2 q0 = sp[0], q1 = sp[1], q2 = sp[2], q3 = sp[3];
  float2 x0 = xt[q0.x], x1 = xt[q1.x];
  float la_=0.f, lb_=0.f, s1a=0.f, s1b=0.f, sta=0.f, stb=0.f;
  int npair = cnt >> 1;
  for (int p=0; p<npair; ++p){
    int i = p*2;
    float2 x2 = xt[q2.x], x3 = xt[q3.x];
    int2 q4 = sp[i+4], q5 = sp[i+5];
    float xs0=x0.x, tf0=x0.y, ea0=__int_as_float(q0.y);
    float xs1=x1.x, tf1=x1.y, ea1=__int_as_float(q1.y);
    float p0a=0.f,p0b=0.f,p1a=0.f,p1b=0.f;
#pragma unroll
    for (int v=0; v<8; ++v){
      float z0 = fmaf(xs0, ul[v], fmaf(ea0, wev[v], fmaf(tf0, cnd[v], cn0[v])));
      float z1 = fmaf(xs1, ul[v], fmaf(ea1, wev[v], fmaf(tf1, cnd[v], cn0[v])));
      p0a = fmaf(a1[v], z0, p0a); p0b = fmaf(a2[v], fabsf(z0), p0b);
      p1a = fmaf(a1[v], z1, p1a); p1b = fmaf(a2[v], fabsf(z1), p1b);
    }
    float p0 = p0a+p0b, p1 = p1a+p1b;
#pragma unroll
    for (int mm=1; mm<16; mm<<=1){
      p0 += __shfl_xor(p0, mm, 16);
      p1 += __shfl_xor(p1, mm, 16);
    }
    float pe0 = __expf(p0), pe1 = __expf(p1);
    la_ += pe0; lb_ += pe1;
    s1a = fmaf(pe0, xs0, s1a); s1b = fmaf(pe1, xs1, s1b);
    sta = fmaf(pe0, tf0, sta); stb = fmaf(pe1, tf1, stb);
    q0=q2; x0=x2; q1=q3; x1=x3; q2=q4; q3=q5;
  }
  if (cnt & 1){
    float xs0=x0.x, tf0=x0.y, ea0=__int_as_float(q0.y);
    float p0a=0.f,p0b=0.f;
#pragma unroll
    for (int v=0; v<8; ++v){
      float z0 = fmaf(xs0, ul[v], fmaf(ea0, wev[v], fmaf(tf0, cnd[v], cn0[v])));
      p0a = fmaf(a1[v], z0, p0a); p0b = fmaf(a2[v], fabsf(z0), p0b);
    }
    float p0 = p0a+p0b;
#pragma unroll
    for (int mm=1; mm<16; mm<<=1) p0 += __shfl_xor(p0, mm, 16);
    float pe0 = __expf(p0);
    la_ += pe0; s1a = fmaf(pe0, xs0, s1a); sta = fmaf(pe0, tf0, sta);
  }
  float inv = 1.f/(la_+lb_);
  float s1 = (s1a+s1b)*inv;
  float s21 = (sta+stb)*inv;     // weight of type-1 sources
  float s20 = 1.f - s21;         // weight of type-0 sources
  bf16x8 ov;
#pragma unroll
  for (int v=0; v<8; ++v){
    float c0 = CTl[ch0+v], c1 = CTl[1024+ch0+v];
    float o = lrelu(fmaf(s1, ul[v], fmaf(s20, c0, fmaf(s21, c1, bias[ch0+v]))));
    ov[v] = (short)f2bf(o);
  }
  *(bf16x8*)(out + (size_t)n*1024 + ch0) = ov;
}

// ---------------- generic fused GATv2 conv, QUAD-stream, plain-exp softmax ------------
// Self-augmented CSR: all cnt edges (self first) are real se entries -> branch-free
// quad loop, remainder masked via val[k] (junk gathers read valid node ids from
// neighbor rows / pad). att*lrelu fold: 4 VALU/ch with dual accumulator chains.
template<int H, int NPB, int VPT, bool ONLY0, bool OUTBF, bool INBF>
__global__ __launch_bounds__(64*NPB) void conv_kernel(
    const int* __restrict__ rowptr, const int2* __restrict__ se,
    const int* __restrict__ ntype,
    const void* __restrict__ Xv, int stride, int xr_off,
    const float* __restrict__ we, const float* __restrict__ att, const float* __restrict__ bias,
    void* __restrict__ out)
{
  const int HC = 64*VPT;
  const int TPH = 64/H;
  int n = blockIdx.x*NPB + (threadIdx.x >> 6);
  if (n >= NN) return;
  if (ONLY0 && ntype[n] != 0) return;
  int tid = threadIdx.x & 63;
  int ch0 = tid * VPT;
  const float* Xf = (const float*)Xv;
  const unsigned short* Xb = (const unsigned short*)Xv;
  float wev[VPT], a1v[VPT], a2v[VPT], biv[VPT], xrv[VPT];
#pragma unroll
  for (int v=0; v<VPT; ++v){
    int ch = ch0+v;
    wev[v]=we[ch]; biv[v]=bias[ch];
    float av = att[ch]; a1v[v]=0.6f*av; a2v[v]=0.4f*av;
  }
  if constexpr (INBF){
    ushort4 q = *(const ushort4*)(Xb + (size_t)n*stride + xr_off + ch0);
    xrv[0]=bf2f(q.x); xrv[1]=bf2f(q.y); xrv[2]=bf2f(q.z); xrv[3]=bf2f(q.w);
  } else {
#pragma unroll
    for (int v=0; v<VPT; ++v) xrv[v]=Xf[(size_t)n*stride + xr_off + ch0+v];
  }
  float ls[4], A[4][VPT];
#pragma unroll
  for (int k=0; k<4; ++k){
    ls[k] = 0.f;
#pragma unroll
    for (int v=0; v<VPT; ++v) A[k][v] = 0.f;
  }
  int beg=rowptr[n], end=rowptr[n+1];   // [beg,end): self + real edges
  for (int j=beg; j<end; j+=4){
    bool val[4]; int sx[4]; float ex[4];
#pragma unroll
    for (int k=0; k<4; ++k){
      int pos = j + k;
      val[k] = pos < end;
      int2 q = se[pos];                  // unconditional (padded; junk masked below)
      sx[k] = q.x; ex[k] = __int_as_float(q.y);
    }
    float xv[4][VPT];
#pragma unroll
    for (int k=0; k<4; ++k){
      if constexpr (INBF){
        ushort4 q = *(const ushort4*)(Xb + (size_t)sx[k]*stride + ch0);
        xv[k][0]=bf2f(q.x); xv[k][1]=bf2f(q.y); xv[k][2]=bf2f(q.z); xv[k][3]=bf2f(q.w);
      } else if constexpr (VPT == 4){
        float4 q = *(const float4*)(Xf + (size_t)sx[k]*stride + ch0);
        xv[k][0]=q.x; xv[k][1]=q.y; xv[k][2]=q.z; xv[k][3]=q.w;
      } else {
        float2 q = *(const float2*)(Xf + (size_t)sx[k]*stride + ch0);
        xv[k][0]=q.x; xv[k][1]=q.y;
      }
    }
    float p[4];
#pragma unroll
    for (int k=0; k<4; ++k){
      float pa = 0.f, pb = 0.f;
#pragma unroll
      for (int v=0; v<VPT; ++v){
        float z = fmaf(ex[k], wev[v], xv[k][v]+xrv[v]);
        pa = fmaf(a1v[v], z, pa);
        pb = fmaf(a2v[v], fabsf(z), pb);
      }
      p[k] = pa + pb;
    }
#pragma unroll
    for (int mm=1; mm<TPH; mm<<=1){
#pragma unroll
      for (int k=0; k<4; ++k) p[k] += __shfl_xor(p[k], mm, 64);
    }
#pragma unroll
    for (int k=0; k<4; ++k){
      float pe = val[k] ? __expf(p[k]) : 0.f;
      ls[k] += pe;
#pragma unroll
      for (int v=0; v<VPT; ++v) A[k][v] = fmaf(pe, xv[k][v], A[k][v]);
    }
  }
  float lt = (ls[0]+ls[1]) + (ls[2]+ls[3]);
  float inv = 1.f/lt;
  size_t baseo=(size_t)n*HC+ch0;
  if constexpr (OUTBF){
    unsigned short* ob = (unsigned short*)out;
    ushort4 o;
    o.x = f2bf(lrelu(((A[0][0]+A[1][0])+(A[2][0]+A[3][0]))*inv+biv[0]));
    o.y = f2bf(lrelu(((A[0][1]+A[1][1])+(A[2][1]+A[3][1]))*inv+biv[1]));
    o.z = f2bf(lrelu(((A[0][2]+A[1][2])+(A[2][2]+A[3][2]))*inv+biv[2]));
    o.w = f2bf(lrelu(((A[0][3]+A[1][3])+(A[2][3]+A[3][3]))*inv+biv[3]));
    *(ushort4*)(ob + baseo) = o;
  } else {
    float* of = (float*)out;
#pragma unroll
    for (int v=0; v<VPT; ++v)
      of[baseo+v] = lrelu(((A[0][v]+A[1][v])+(A[2][v]+A[3][v]))*inv+biv[v]);
  }
}

// ---------------- bf16 MFMA dual GEMM, LDS-staged via global_load_lds (m97 style) -----
template<bool OUTBF>
__global__ __launch_bounds__(256) void gemm_dual_lds(
    const short* __restrict__ Abf,
    const short* __restrict__ WlT, const short* __restrict__ WrT,
    const float* __restrict__ bl, const float* __restrict__ br,
    void* __restrict__ Out, int M, int K, int NcH, int cgrid, int rgrid)
{
  __shared__ short lds[12288];    // A: [0,8192) shorts (128 rows x 64), B: [8192,12288)
  int id = blockIdx.x;
  int xcd = id & 7, slot = id >> 3;
  int nb = slot % cgrid;
  int rowgroup = (slot / cgrid) * 8 + xcd;
  if (rowgroup >= rgrid) return;
  int row0 = rowgroup * 128;
  int NC2 = 2*NcH;
  int halfx = NcH >> 6;
  int isR = nb >= halfx;
  const short* WT = isR ? WrT : WlT;
  const float* bias = isR ? br : bl;
  int col0 = (nb - (isR ? halfx : 0)) * 64;
  int gcol0 = nb * 64;
  int tid = threadIdx.x;
  int lane = tid & 63, wave = tid >> 6;
  int wm = wave >> 1, wn = wave & 1;
  int quad = lane >> 4, l16 = lane & 15;

  const short* asrc[4];
#pragma unroll
  for (int i=0;i<4;++i){
    int c = wave*256 + i*64 + lane;
    int m = c >> 3, j = c & 7;
    int gr = row0 + m; gr = gr < M ? gr : M-1;   // clamp; never stored
    asrc[i] = Abf + (size_t)gr*K + ((j ^ (m & 7)) << 3);
  }
  const short* bsrc[2];
#pragma unroll
  for (int i=0;i<2;++i){
    int c = wave*128 + i*64 + lane;
    int nloc = c >> 3, j = c & 7;
    bsrc[i] = WT + (size_t)(col0 + nloc)*K + ((j ^ (nloc & 7)) << 3);
  }

  float biasv[2] = { bias[col0 + wn*32 + l16], bias[col0 + wn*32 + 16 + l16] };
  f32x4 acc[4][2];
#pragma unroll
  for (int f=0; f<4; ++f)
#pragma unroll
    for (int g=0; g<2; ++g) acc[f][g] = (f32x4){0.f,0.f,0.f,0.f};

  int niter = K >> 6;
  for (int it=0; it<niter; ++it){
    int k0 = it << 6;
#pragma unroll
    for (int i=0;i<4;++i)
      __builtin_amdgcn_global_load_lds(asrc[i] + k0, &lds[(wave*256 + i*64)*8], 16, 0, 0);
#pragma unroll
    for (int i=0;i<2;++i)
      __builtin_amdgcn_global_load_lds(bsrc[i] + k0, &lds[8192 + (wave*128 + i*64)*8], 16, 0, 0);
    __syncthreads();
#pragma unroll
    for (int s=0; s<2; ++s){
      int t = s*4 + quad;
      bf16x8 af[4], bfv[2];
#pragma unroll
      for (int f=0; f<4; ++f){
        int m = wm*64 + f*16 + l16;
        af[f] = *(const bf16x8*)&lds[m*64 + ((t ^ (m & 7)) << 3)];
      }
#pragma unroll
      for (int g=0; g<2; ++g){
        int nloc = wn*32 + g*16 + l16;
        bfv[g] = *(const bf16x8*)&lds[8192 + nloc*64 + ((t ^ (nloc & 7)) << 3)];
      }
#pragma unroll
      for (int f=0; f<4; ++f)
#pragma unroll
        for (int g=0; g<2; ++g)
          acc[f][g] = __builtin_amdgcn_mfma_f32_16x16x32_bf16(af[f], bfv[g], acc[f][g], 0,0,0);
    }
    __syncthreads();
  }

#pragma unroll
  for (int f=0; f<4; ++f){
    int rbase = row0 + wm*64 + f*16 + quad*4;
#pragma unroll
    for (int r=0; r<4; ++r){
      int rr = rbase + r;
      if (rr < M){
#pragma unroll
        for (int g=0; g<2; ++g){
          int cc = gcol0 + wn*32 + g*16 + l16;
          float val = acc[f][g][r] + biasv[g];
          if constexpr (OUTBF) ((unsigned short*)Out)[(size_t)rr*NC2 + cc] = f2bf(val);
          else                 ((float*)Out)[(size_t)rr*NC2 + cc] = val;
        }
      }
    }
  }
}

// ---------------- fused pool (sorted batch, binary search) + MLP head ----------------
__device__ __forceinline__ int lbound(const int* __restrict__ a, int n, int key){
  int lo = 0, hi = n;
  while (lo < hi){ int mid = (lo+hi) >> 1; if (a[mid] < key) lo = mid+1; else hi = mid; }
  return lo;
}

__global__ __launch_bounds__(128) void head_kernel(
    const float* __restrict__ h3, const int* __restrict__ ntype, const int* __restrict__ batch,
    const float* __restrict__ m1w, const float* __restrict__ m1b,
    const float* __restrict__ g1, const float* __restrict__ b1,
    const float* __restrict__ m2w, const float* __restrict__ m2b,
    const float* __restrict__ g2, const float* __restrict__ b2,
    const float* __restrict__ m3w, const float* __restrict__ m3b,
    float* __restrict__ out)
{
  __shared__ float p[128];
  __shared__ float hb[128];
  __shared__ float red[128];
  int b = blockIdx.x, j = threadIdx.x;
  int lo = lbound(batch, NN, b);
  int hi = lbound(batch, NN, b+1);
  float s = 0.f, cnt = 0.f;
  int n = lo;
  for (; n + 3 < hi; n += 4){
    float w0 = (ntype[n]   == 0) ? 1.f : 0.f;
    float w1 = (ntype[n+1] == 0) ? 1.f : 0.f;
    float w2 = (ntype[n+2] == 0) ? 1.f : 0.f;
    float w3 = (ntype[n+3] == 0) ? 1.f : 0.f;
    s += w0*h3[(size_t)n*128 + j]     + w1*h3[(size_t)(n+1)*128 + j]
       + w2*h3[(size_t)(n+2)*128 + j] + w3*h3[(size_t)(n+3)*128 + j];
    cnt += w0 + w1 + w2 + w3;
  }
  for (; n < hi; ++n){
    float w = (ntype[n] == 0) ? 1.f : 0.f;
    s += w*h3[(size_t)n*128 + j];
    cnt += w;
  }
  p[j] = s / fmaxf(cnt, 1.f);
  __syncthreads();
  float a = m1b[j];
  for (int k=0; k<128; ++k) a += p[k]*m1w[k*128 + j];
  red[j] = a; __syncthreads();
  for (int off=64; off>0; off>>=1){ if (j<off) red[j] += red[j+off]; __syncthreads(); }
  float mu = red[0] * (1.f/128.f);
  __syncthreads();
  float d = a - mu;
  red[j] = d*d; __syncthreads();
  for (int off=64; off>0; off>>=1){ if (j<off) red[j] += red[j+off]; __syncthreads(); }
  float var = red[0] * (1.f/128.f);
  __syncthreads();
  hb[j] = lrelu(d * rsqrtf(var + 1e-5f) * g1[j] + b1[j]);
  __syncthreads();
  float a2 = 0.f;
  if (j < 64){
    a2 = m2b[j];
    for (int k=0; k<128; ++k) a2 += hb[k]*m2w[k*64 + j];
  }
  red[j] = (j<64) ? a2 : 0.f; __syncthreads();
  for (int off=64; off>0; off>>=1){ if (j<off) red[j] += red[j+off]; __syncthreads(); }
  float mu2 = red[0] * (1.f/64.f);
  __syncthreads();
  float d2 = a2 - mu2;
  red[j] = (j<64) ? d2*d2 : 0.f; __syncthreads();
  for (int off=64; off>0; off>>=1){ if (j<off) red[j] += red[j+off]; __syncthreads(); }
  float var2 = red[0] * (1.f/64.f);
  __syncthreads();
  if (j < 64) hb[j] = lrelu(d2 * rsqrtf(var2 + 1e-5f) * g2[j] + b2[j]);
  __syncthreads();
  if (j == 0){
    float o = m3b[0];
    for (int k=0; k<64; ++k) o += hb[k]*m3w[k];
    out[b] = o;
  }
}

extern "C" void kernel_launch(void* const* d_in, const int* in_sizes, int n_in,
                              void* d_out, int out_size, void* d_ws, size_t ws_size,
                              hipStream_t stream)
{
  const float* x        = (const float*)d_in[0];
  const int*   ntype    = (const int*)d_in[1];
  const int*   ei       = (const int*)d_in[2];
  const float* eattr    = (const float*)d_in[3];
  const int*   batch    = (const int*)d_in[4];
  const float* vp_w     = (const float*)d_in[5];
  const float* vp_b     = (const float*)d_in[6];
  const float* type_emb = (const float*)d_in[7];
  const float* c1_wl = (const float*)d_in[8];  const float* c1_bl = (const float*)d_in[9];
  const float* c1_wr = (const float*)d_in[10]; const float* c1_br = (const float*)d_in[11];
  const float* c1_we = (const float*)d_in[12]; const float* c1_att= (const float*)d_in[13];
  const float* c1_bias=(const float*)d_in[14];
  const float* c2_wl = (const float*)d_in[15]; const float* c2_bl = (const float*)d_in[16];
  const float* c2_wr = (const float*)d_in[17]; const float* c2_br = (const float*)d_in[18];
  const float* c2_we = (const float*)d_in[19]; const float* c2_att= (const float*)d_in[20];
  const float* c2_bias=(const float*)d_in[21];
  const float* c3_wl = (const float*)d_in[22]; const float* c3_bl = (const float*)d_in[23];
  const float* c3_wr = (const float*)d_in[24]; const float* c3_br = (const float*)d_in[25];
  const float* c3_we = (const float*)d_in[26]; const float* c3_att= (const float*)d_in[27];
  const float* c3_bias=(const float*)d_in[28];
  const float* m1_w = (const float*)d_in[29]; const float* m1_b = (const float*)d_in[30];
  const float* ln1_g= (const float*)d_in[31]; const float* ln1_b= (const float*)d_in[32];
  const float* m2_w = (const float*)d_in[33]; const float* m2_b = (const float*)d_in[34];
  const float* ln2_g= (const float*)d_in[35]; const float* ln2_b= (const float*)d_in[36];
  const float* m3_w = (const float*)d_in[37]; const float* m3_b = (const float*)d_in[38];
  const int* esrc = ei;
  const int* edst = ei + NE;
  float* outp = (float*)d_out;
  (void)in_sizes; (void)n_in; (void)out_size; (void)ws_size;

  // ---- workspace arena ----
  char* w = (char*)d_ws;
  auto alloc = [&](size_t bytes) -> void* {
    void* p = (void*)w;
    w += (bytes + 255) & ~(size_t)255;
    return p;
  };
  unsigned short* h1bf = (unsigned short*)alloc((size_t)NN*1024*2);  // conv1 out, bf16
  unsigned short* X2   = (unsigned short*)alloc((size_t)NN*512*2);   // [xl2 | xr2] bf16
  unsigned short* h2bf = (unsigned short*)alloc((size_t)NN*256*2);   // conv2 out, bf16
  float* X3   = (float*)alloc((size_t)NN*256*4);    // [xl3 | xr3] fp32
  float* h3   = (float*)alloc((size_t)NN*128*4);    // conv3 out (type0 rows only)
  unsigned short* W2lT = (unsigned short*)alloc((size_t)256*1024*2);
  unsigned short* W2rT = (unsigned short*)alloc((size_t)256*1024*2);
  unsigned short* W3lT = (unsigned short*)alloc((size_t)128*256*2);
  unsigned short* W3rT = (unsigned short*)alloc((size_t)128*256*2);
  float* Ul   = (float*)alloc(1024*4);
  float* CTl  = (float*)alloc(2048*4);
  float* Ur   = (float*)alloc(1024*4);
  float* CTr  = (float*)alloc(2048*4);
  const int zero_words = 3*NN;                       // deg, rowctr, loop_sum
  float* zbase = (float*)alloc((size_t)zero_words*4);
  int*   deg      = (int*)zbase;
  int*   rowctr   = (int*)(zbase + NN);
  float* loop_sum = zbase + 2*NN;
  float2* xt      = (float2*)alloc((size_t)NN*8);    // {x, (float)ntype}
  int*   rowptr   = (int*)alloc((size_t)(NN+1)*4);   // self-augmented rowptr2
  int2*  se       = (int2*)alloc((size_t)(E2+8)*8);  // self+edges CSR, +8 pad

  // ---- pipeline (10 dispatches) ----
  prep_kernel<<<180, 256, 0, stream>>>(vp_w, vp_b, type_emb,
      c1_wl, c1_bl, c1_wr, c1_br, Ul, CTl, Ur, CTr,
      c2_wl, c2_wr, c3_wl, c3_wr, W2lT, W2rT, W3lT, W3rT,
      zbase, zero_words);
  count_kernel<<<(NE+255)/256, 256, 0, stream>>>(edst, eattr, deg, loop_sum);
  scan_kernel<<<1, 1024, 0, stream>>>(deg, loop_sum, x, ntype, rowptr, se, xt);
  fill_kernel<<<(NE+255)/256, 256, 0, stream>>>(esrc, edst, eattr, rowptr, rowctr, se);
  conv1_fused<<<NN/2, 256, 0, stream>>>(rowptr, se, xt,
      Ul, Ur, CTl, CTr, c1_we, c1_att, c1_bias, h1bf);
  // c2: X2[10000,512] bf16, K=1024, NcH=256: cgrid=8, rgrid=79 -> 640 blocks
  gemm_dual_lds<true><<<640, 256, 0, stream>>>(
      (const short*)h1bf, (const short*)W2lT, (const short*)W2rT, c2_bl, c2_br,
      (void*)X2, NN, 1024, 256, 8, 79);
  conv_kernel<2,4,4,false,true,true><<<NN/4, 256, 0, stream>>>(rowptr, se, ntype,
      (const void*)X2, 512, 256, c2_we, c2_att, c2_bias, h2bf);
  // c3: X3[10000,256] fp32, K=256, NcH=128: cgrid=4, rgrid=79 -> 320 blocks
  gemm_dual_lds<false><<<320, 256, 0, stream>>>(
      (const short*)h2bf, (const short*)W3lT, (const short*)W3rT, c3_bl, c3_br,
      (void*)X3, NN, 256, 128, 4, 79);
  conv_kernel<1,4,2,true,false,false><<<NN/4, 256, 0, stream>>>(rowptr, se, ntype,
      (const void*)X3, 256, 128, c3_we, c3_att, c3_bias, h3);
  head_kernel<<<NBATCH, 128, 0, stream>>>(h3, ntype, batch, m1_w, m1_b, ln1_g, ln1_b,
                                          m2_w, m2_b, ln2_g, ln2_b, m3_w, m3_b, outp);
}